// Round 1
// baseline (103.478 us; speedup 1.0000x reference)
//
#include <hip/hip_runtime.h>

// Chamfer distance, B=16, N=M=4096, 2-D fp32 points, prefix-length masks.
// d_out layout: [fwd 16*4096][bwd 16*4096] fp32.
//
// Strategy: d2 = (t2 - 2*q.t) + s2 -> inner pair = 2 fma + 1 min (3 VALU).
// Per block: (batch, 1024-query chunk, 1024-target chunk). Target chunk staged
// in LDS as float4(tx,ty,t2,pad). 4 query points per thread amortize each
// ds_read_b128 over 12 VALU ops. Partial mins merged with atomicMin on the
// IEEE bit pattern of the clamped (>=0) d2, stored in d_out itself; an init
// kernel seeds bits(1e10) and the epilogue does sqrt + validity masking
// in place. Lt==0 => slot stays 1e10 => sqrt=1e5, matching the reference.

#define BIGF 1e10f

__global__ __launch_bounds__(256) void chamfer_init(unsigned int* __restrict__ out_bits) {
    int idx = blockIdx.x * 256 + threadIdx.x;
    out_bits[idx] = __float_as_uint(BIGF);
}

__global__ __launch_bounds__(256) void chamfer_main(
    const float* __restrict__ src, const float* __restrict__ tgt,
    const int* __restrict__ slen, const int* __restrict__ tlen,
    unsigned int* __restrict__ out_bits)
{
    __shared__ float4 sh[1024];  // (tx, ty, t2, pad) per staged point

    const int bx  = blockIdx.x;
    const int dir = bx >> 8;         // 0: fwd (query=src, search tgt), 1: bwd
    const int b   = (bx >> 4) & 15;  // batch
    const int qc  = (bx >> 2) & 3;   // query chunk (1024 points)
    const int pc  = bx & 3;          // search-point chunk (1024 points)
    const int tid = threadIdx.x;

    const float* Q = dir ? tgt : src;
    const float* P = dir ? src : tgt;
    const int Lq = dir ? tlen[b] : slen[b];
    const int Lp = dir ? slen[b] : tlen[b];

    // Stage 1024 search points (4 per thread) with precomputed |t|^2.
    const float4* p4 = (const float4*)(P + (size_t)(b * 4096 + pc * 1024) * 2);
    float4 a = p4[tid * 2];
    float4 c = p4[tid * 2 + 1];
    sh[tid * 4 + 0] = make_float4(a.x, a.y, fmaf(a.x, a.x, a.y * a.y), 0.f);
    sh[tid * 4 + 1] = make_float4(a.z, a.w, fmaf(a.z, a.z, a.w * a.w), 0.f);
    sh[tid * 4 + 2] = make_float4(c.x, c.y, fmaf(c.x, c.x, c.y * c.y), 0.f);
    sh[tid * 4 + 3] = make_float4(c.z, c.w, fmaf(c.z, c.z, c.w * c.w), 0.f);
    __syncthreads();

    int count = Lp - pc * 1024;                      // valid points in this chunk
    count = count < 0 ? 0 : (count > 1024 ? 1024 : count);

    // 4 query points per thread (coalesced float2 loads).
    float m2x[4], m2y[4], s2[4], best[4];
    int iq[4];
    #pragma unroll
    for (int k = 0; k < 4; ++k) {
        const int i = qc * 1024 + tid + k * 256;
        iq[k] = i;
        const float2 q = ((const float2*)Q)[b * 4096 + i];
        m2x[k] = -2.f * q.x;
        m2y[k] = -2.f * q.y;
        s2[k]  = fmaf(q.x, q.x, q.y * q.y);
        best[k] = 3.0e38f;
    }

    #pragma unroll 4
    for (int j = 0; j < count; ++j) {
        const float4 t = sh[j];
        #pragma unroll
        for (int k = 0; k < 4; ++k) {
            float v = fmaf(m2x[k], t.x, t.z);   // t2 - 2*qx*tx
            v = fmaf(m2y[k], t.y, v);           // t2 - 2*q.t
            best[k] = fminf(best[k], v);
        }
    }

    if (count > 0) {
        unsigned int* row = out_bits + dir * 65536 + b * 4096;
        #pragma unroll
        for (int k = 0; k < 4; ++k) {
            if (iq[k] < Lq) {
                const float d2 = fmaxf(best[k] + s2[k], 0.f);  // clamp commutes with min
                atomicMin(&row[iq[k]], __float_as_uint(d2));   // nonneg float bits are order-preserving
            }
        }
    }
}

__global__ __launch_bounds__(256) void chamfer_epilogue(
    unsigned int* __restrict__ out_bits,
    const int* __restrict__ slen, const int* __restrict__ tlen)
{
    int idx = blockIdx.x * 256 + threadIdx.x;
    const int dir = idx >> 16;
    const int b   = (idx >> 12) & 15;
    const int i   = idx & 4095;
    const int L   = dir ? tlen[b] : slen[b];
    float r = 0.f;
    if (i < L) r = sqrtf(__uint_as_float(out_bits[idx]));
    ((float*)out_bits)[idx] = r;   // in-place: one thread per element
}

extern "C" void kernel_launch(void* const* d_in, const int* in_sizes, int n_in,
                              void* d_out, int out_size, void* d_ws, size_t ws_size,
                              hipStream_t stream) {
    const float* src = (const float*)d_in[0];   // [16,4096,2] f32
    const float* tgt = (const float*)d_in[1];   // [16,4096,2] f32
    const int* slen  = (const int*)d_in[2];     // [16] i32
    const int* tlen  = (const int*)d_in[3];     // [16] i32
    unsigned int* out_bits = (unsigned int*)d_out;  // 131072 elems

    chamfer_init<<<512, 256, 0, stream>>>(out_bits);
    chamfer_main<<<512, 256, 0, stream>>>(src, tgt, slen, tlen, out_bits);
    chamfer_epilogue<<<512, 256, 0, stream>>>(out_bits, slen, tlen);
}

// Round 2
// 90.829 us; speedup vs baseline: 1.1393x; 1.1393x over previous
//
#include <hip/hip_runtime.h>

// Chamfer distance, B=16, N=M=4096, 2-D fp32 points, prefix-length masks.
// d_out layout: [fwd 16*4096][bwd 16*4096] fp32.
//
// R2: round-1 counters showed LDS read BW (not VALU) was the ceiling:
// ds_read_b128 is ~12 cyc/wave/CU and served only 12 VALU instrs (4 queries).
// Now 16 queries/thread -> 48 VALU per ds_read, LDS drops to ~50% of VALU.
// Grid = 2(dir) x 16(batch) x 16(target chunk of 256); each block covers a
// full 4096-query row (16 q/thread x 256 threads). Partial mins merged via
// atomicMin on IEEE bits of the clamped (>=0) d2 into d_out, initialized to
// 0xFFFFFFFF by hipMemsetAsync (replaces the init kernel). Epilogue does
// sqrt + masking in place; untouched slots (Lp==0) = 0xFFFFFFFF -> 1e5,
// matching sqrt(BIG) in the reference.

#define NQ 16  // queries per thread

__global__ __launch_bounds__(256, 2) void chamfer_main(
    const float* __restrict__ src, const float* __restrict__ tgt,
    const int* __restrict__ slen, const int* __restrict__ tlen,
    unsigned int* __restrict__ out_bits)
{
    __shared__ float4 sh[256];  // (tx, ty, t2, pad)

    const int bx  = blockIdx.x;
    const int dir = bx >> 8;         // 0: fwd (query=src, search tgt), 1: bwd
    const int b   = (bx >> 4) & 15;  // batch
    const int pc  = bx & 15;         // search-point chunk (256 points)
    const int tid = threadIdx.x;

    const float* Q = dir ? tgt : src;
    const float* P = dir ? src : tgt;
    const int Lp = dir ? slen[b] : tlen[b];

    // Stage 256 search points with precomputed |t|^2 (once per block).
    {
        const float2 p = ((const float2*)P)[b * 4096 + pc * 256 + tid];
        sh[tid] = make_float4(p.x, p.y, fmaf(p.x, p.x, p.y * p.y), 0.f);
    }
    __syncthreads();

    int count = Lp - pc * 256;           // valid points in this chunk
    count = count < 0 ? 0 : (count > 256 ? 256 : count);
    if (count == 0) return;              // no contribution from this chunk

    // 16 query points per thread (coalesced float2 loads), full row.
    float m2x[NQ], m2y[NQ], s2[NQ], best[NQ];
    #pragma unroll
    for (int k = 0; k < NQ; ++k) {
        const float2 q = ((const float2*)Q)[b * 4096 + tid + k * 256];
        m2x[k] = -2.f * q.x;
        m2y[k] = -2.f * q.y;
        s2[k]  = fmaf(q.x, q.x, q.y * q.y);
        best[k] = 3.0e38f;
    }

    // Inner loop: 1 ds_read_b128 + 48 VALU (3 per query) per point.
    #pragma unroll 4
    for (int j = 0; j < count; ++j) {
        const float4 t = sh[j];
        #pragma unroll
        for (int k = 0; k < NQ; ++k) {
            float v = fmaf(m2x[k], t.x, t.z);   // t2 - 2*qx*tx
            v = fmaf(m2y[k], t.y, v);           // t2 - 2*q.t
            best[k] = fminf(best[k], v);
        }
    }

    unsigned int* row = out_bits + dir * 65536 + b * 4096;
    #pragma unroll
    for (int k = 0; k < NQ; ++k) {
        const float d2 = fmaxf(best[k] + s2[k], 0.f);  // clamp commutes with min
        atomicMin(&row[tid + k * 256], __float_as_uint(d2));  // nonneg bits order-preserving
    }
}

__global__ __launch_bounds__(256) void chamfer_epilogue(
    unsigned int* __restrict__ out_bits,
    const int* __restrict__ slen, const int* __restrict__ tlen)
{
    const int idx = blockIdx.x * 256 + threadIdx.x;
    const int dir = idx >> 16;
    const int b   = (idx >> 12) & 15;
    const int i   = idx & 4095;
    const int L   = dir ? tlen[b] : slen[b];
    float r = 0.f;
    if (i < L) {
        const unsigned int bits = out_bits[idx];
        r = (bits == 0xFFFFFFFFu) ? 100000.0f   // empty search set: sqrt(1e10)
                                  : sqrtf(__uint_as_float(bits));
    }
    ((float*)out_bits)[idx] = r;   // in-place, one thread per element
}

extern "C" void kernel_launch(void* const* d_in, const int* in_sizes, int n_in,
                              void* d_out, int out_size, void* d_ws, size_t ws_size,
                              hipStream_t stream) {
    const float* src = (const float*)d_in[0];   // [16,4096,2] f32
    const float* tgt = (const float*)d_in[1];   // [16,4096,2] f32
    const int* slen  = (const int*)d_in[2];     // [16] i32
    const int* tlen  = (const int*)d_in[3];     // [16] i32
    unsigned int* out_bits = (unsigned int*)d_out;  // 131072 elems

    hipMemsetAsync(out_bits, 0xFF, (size_t)131072 * 4, stream);  // atomicMin identity
    chamfer_main<<<512, 256, 0, stream>>>(src, tgt, slen, tlen, out_bits);
    chamfer_epilogue<<<512, 256, 0, stream>>>(out_bits, slen, tlen);
}